// Round 11
// baseline (144.856 us; speedup 1.0000x reference)
//
#include <hip/hip_runtime.h>
#include <stdint.h>

// LmHead: RMSNorm(8x4096) -> logits = h @ W^T (W: 32000x4096 f32) -> argmax per row.
// Memory-bound: W is 524 MB -> HBM read stream. Best: R4 = 125.8us (kernel B
//   ~122us = 4.3 TB/s). Fill-kernel write calibration 6.5 TB/s; read ceiling TBD.
// R9/R10: plain W (+/- twin-wave reuse) = +9us penalty, reuse neutral ->
//   h-traffic and W-reuse are NOT limiters; nt stays.
// R5 (168us)/R8 (174us): depth-2 W regressed WITHOUT occupancy caps ->
//   hypothesis: compiler clustered the 72 loads of the big body across phases
//   (it reorders independent vmem freely), blowing live ranges / issue order.
// R11 = R8 + __builtin_amdgcn_sched_barrier(0) fences around each phase's
//   load block and compute block: placement pinned, per-phase live set
//   bounded, counted vmcnt(16) with W age = 2 phases (covers ~1800cyc >> HBM).

#define D 4096
#define BATCH 8
#define VOCAB 32000
#define VT 4                 // vocab rows per wave
#define NBLK 2000            // 4 waves/block -> 8000 waves, exactly 1 group per wave
#define EPS 1e-6f

typedef unsigned long long u64;
typedef float f32x4 __attribute__((ext_vector_type(4)));

#define SB __builtin_amdgcn_sched_barrier(0)

// ---------------- Kernel A: RMSNorm -> h in workspace ----------------
__global__ __launch_bounds__(256) void rmsnorm_k(const float* __restrict__ x,
                                                 const float* __restrict__ g,
                                                 float* __restrict__ h) {
    const int b = blockIdx.x;
    const int t = threadIdx.x;
    const int wave = t >> 6, lane = t & 63;
    const float* xr = x + b * D;

    f32x4 xv[4];
    float s = 0.f;
#pragma unroll
    for (int i = 0; i < 4; ++i) {
        xv[i] = *(const f32x4*)(xr + i * 1024 + t * 4);
        s += xv[i].x * xv[i].x + xv[i].y * xv[i].y + xv[i].z * xv[i].z + xv[i].w * xv[i].w;
    }
#pragma unroll
    for (int m = 1; m < 64; m <<= 1) s += __shfl_xor(s, m, 64);

    __shared__ float wsum[4];
    if (lane == 0) wsum[wave] = s;
    __syncthreads();
    const float tot = wsum[0] + wsum[1] + wsum[2] + wsum[3];
    const float rs = rsqrtf(tot * (1.f / (float)D) + EPS);

#pragma unroll
    for (int i = 0; i < 4; ++i) {
        const int d = i * 1024 + t * 4;
        const f32x4 gv = *(const f32x4*)(g + d);
        f32x4 o;
        o.x = xv[i].x * rs * gv.x;
        o.y = xv[i].y * rs * gv.y;
        o.z = xv[i].z * rs * gv.z;
        o.w = xv[i].w * rs * gv.w;
        *(f32x4*)(h + b * D + d) = o;
    }
}

// ---- Kernel B: depth-2 W (w0/w1/w2) + depth-1 h (hA/hB), fenced phases ----
__global__ __launch_bounds__(256) void gemv_argmax_k(const float* __restrict__ W,
                                                     const float* __restrict__ h,
                                                     u64* __restrict__ partial) {
    const int lane = threadIdx.x & 63;
    const int wave = threadIdx.x >> 6;
    const int grp = blockIdx.x * 4 + wave;       // [0, 8000)
    const int v0 = grp * VT;
    const float* Wb = W + (size_t)v0 * D;
    const int dl = lane * 4;

    float acc[32];
#pragma unroll
    for (int i = 0; i < 32; ++i) acc[i] = 0.f;

    f32x4 hA[8], hB[8];            // h ping-pong, 1 phase ahead (L2-hot, plain)
    f32x4 w0[VT], w1[VT], w2[VT];  // W triple buffer, 2 phases ahead (nt)

#define LOADH(HB, c)                                                           \
    {                                                                          \
        const int _d = (c) * 256 + dl;                                         \
        _Pragma("unroll")                                                      \
        for (int b = 0; b < 8; ++b)                                            \
            HB[b] = *(const f32x4*)(h + b * D + _d);                           \
    }

#define LOADW(BUF, c)                                                          \
    {                                                                          \
        const int _d = (c) * 256 + dl;                                         \
        _Pragma("unroll")                                                      \
        for (int vi = 0; vi < VT; ++vi)                                        \
            BUF[vi] = __builtin_nontemporal_load((const f32x4*)(Wb + vi * D + _d)); \
    }

#define COMPUTE(HB, WBUF)                                                      \
    {                                                                          \
        _Pragma("unroll")                                                      \
        for (int b = 0; b < 8; ++b) {                                          \
            _Pragma("unroll")                                                  \
            for (int vi = 0; vi < VT; ++vi)                                    \
                acc[b * VT + vi] += WBUF[vi].x * HB[b].x + WBUF[vi].y * HB[b].y + \
                                    WBUF[vi].z * HB[b].z + WBUF[vi].w * HB[b].w;  \
        }                                                                      \
    }

// fenced phase: loads pinned in their phase, compute pinned after them.
#define PHASE(HL, WL, HU, WU, c)                                               \
    LOADH(HL, (c) + 1) LOADW(WL, (c) + 2) SB;                                  \
    COMPUTE(HU, WU) SB;

    // prologue: h(0), W(0), W(1) in flight (oldest first)
    LOADH(hA, 0)
    LOADW(w0, 0)
    LOADW(w1, 1)
    SB;

    // 6-phase rolled body (h period 2, W period 3), c in {0, 6}
#pragma unroll 1
    for (int c = 0; c < 12; c += 6) {
        PHASE(hB, w2, hA, w0, c + 0)
        PHASE(hA, w0, hB, w1, c + 1)
        PHASE(hB, w1, hA, w2, c + 2)
        PHASE(hA, w2, hB, w0, c + 3)
        PHASE(hB, w0, hA, w1, c + 4)
        PHASE(hA, w1, hB, w2, c + 5)
    }
    // tail: phases 12..15
    PHASE(hB, w2, hA, w0, 12)
    PHASE(hA, w0, hB, w1, 13)
    LOADH(hB, 15) SB; COMPUTE(hA, w2) SB;   // c=14 (no W(16))
    COMPUTE(hB, w0) SB;                      // c=15 (nothing left to load)
#undef LOADH
#undef LOADW
#undef COMPUTE
#undef PHASE

    // Butterfly: 32 partials across 64 lanes -> lane l holds total for
    // j = l&31 (b = j>>2, vi = j&3). All indices compile-time.
#pragma unroll
    for (int s = 0; s < 5; ++s) {
        const int m = 1 << s;
        const bool bit = (lane & m) != 0;
#pragma unroll
        for (int u = 0; u < (32 >> (s + 1)); ++u) {
            const float a = acc[2 * u];
            const float c2 = acc[2 * u + 1];
            const float keep = bit ? c2 : a;
            const float send = bit ? a : c2;
            acc[u] = keep + __shfl_xor(send, m, 64);
        }
    }
    const float logit = acc[0] + __shfl_xor(acc[0], 32, 64);  // fold dup halves

    const int vidx = v0 + (lane & 3);
    const uint32_t fb = __float_as_uint(logit);
    const uint32_t key = (fb & 0x80000000u) ? ~fb : (fb | 0x80000000u);
    u64 best = ((u64)key << 32) | (uint32_t)(~(uint32_t)vidx);

    // merge across vi (bits 0,1); halves are duplicates after the fold
#pragma unroll
    for (int m = 1; m <= 2; m <<= 1) {
        const u64 o = __shfl_xor(best, m, 64);
        if (o > best) best = o;
    }
    {
        const u64 o = __shfl_xor(best, 32, 64);
        if (o > best) best = o;
    }

    __shared__ u64 lb[4][8];
    if (lane < 32 && (lane & 3) == 0) lb[wave][lane >> 2] = best;
    __syncthreads();
    if (threadIdx.x < 8) {
        const u64 m0 = lb[0][threadIdx.x], m1 = lb[1][threadIdx.x];
        const u64 m2 = lb[2][threadIdx.x], m3 = lb[3][threadIdx.x];
        const u64 a = m0 > m1 ? m0 : m1;
        const u64 b2 = m2 > m3 ? m2 : m3;
        partial[(size_t)blockIdx.x * 8 + threadIdx.x] = a > b2 ? a : b2;
    }
}

// ---------------- Kernel C: final argmax over block partials ----------------
__global__ __launch_bounds__(512) void finalize_k(const u64* __restrict__ partial,
                                                  int* __restrict__ out, int nblk) {
    const int b = threadIdx.x >> 6;   // one wave per batch row
    const int lane = threadIdx.x & 63;
    u64 best = 0ull;
    for (int p = lane; p < nblk; p += 64) {
        const u64 x = partial[(size_t)p * 8 + b];
        if (x > best) best = x;
    }
#pragma unroll
    for (int m = 1; m < 64; m <<= 1) {
        const u64 o = __shfl_xor(best, m, 64);
        if (o > best) best = o;
    }
    if (lane == 0) out[b] = (int)(~(uint32_t)best);
}

extern "C" void kernel_launch(void* const* d_in, const int* in_sizes, int n_in,
                              void* d_out, int out_size, void* d_ws, size_t ws_size,
                              hipStream_t stream) {
    const float* x = (const float*)d_in[0]; // hidden_states [8,4096]
    const float* g = (const float*)d_in[1]; // norm_weight [4096]
    const float* W = (const float*)d_in[2]; // lm_head_weight [32000,4096]
    int* out = (int*)d_out;                 // [8] int32 token ids

    float* h = (float*)d_ws;                                        // 128 KB
    u64* partial = (u64*)((char*)d_ws + BATCH * D * sizeof(float)); // 2000*8*8B

    rmsnorm_k<<<BATCH, 256, 0, stream>>>(x, g, h);
    gemv_argmax_k<<<NBLK, 256, 0, stream>>>(W, h, partial);
    finalize_k<<<1, 512, 0, stream>>>(partial, out, NBLK);
}

// Round 12
// 131.468 us; speedup vs baseline: 1.1018x; 1.1018x over previous
//
#include <hip/hip_runtime.h>
#include <stdint.h>

// LmHead: RMSNorm(8x4096) -> logits = h @ W^T (W: 32000x4096 f32) -> argmax per row.
// W = 524 MB -> HBM read stream. BEST: R4 = 125.8us (kernel B ~122us = 4.3 TB/s).
// Ledger: R2/R4/R9/R10 all 4.3-4.6 TB/s W-read; R10 (half h-traffic + twin-wave
//   W sharing) NEUTRAL -> h-contention & reuse falsified. Depth-2 W failed 3x
//   (R5/R8/R11) under different controls -> dead. VALU ~8%, coverage ample.
//   Surviving theory: per-CU outstanding-miss (TCP/MSHR) ceiling on the
//   VGPR-return read path (~4.5 TB/s); write path (fills, 6.6) differs.
// R12: probe the OTHER read path -- global_load_lds DMA (m97's staging lever).
//   Wave-private protocol, no barriers: wave DMAs its own 4 rows' 1KB chunks
//   to its LDS slice; h stays in R4's VGPR ping-pong. Compiler can't see
//   DMA->ds_read deps -> explicit asm s_waitcnt vmcnt(12) + sched_barrier(0)
//   fences (its own h-wait vmcnt(16) would NOT cover the DMA).

#define D 4096
#define BATCH 8
#define VOCAB 32000
#define VT 4                 // rows per wave
#define NBLK 2000            // 16 rows per block x 2000 = 32000
#define EPS 1e-6f

typedef unsigned long long u64;
typedef float f32x4 __attribute__((ext_vector_type(4)));

#define SB __builtin_amdgcn_sched_barrier(0)

// ---------------- Kernel A: RMSNorm -> h in workspace ----------------
__global__ __launch_bounds__(256) void rmsnorm_k(const float* __restrict__ x,
                                                 const float* __restrict__ g,
                                                 float* __restrict__ h) {
    const int b = blockIdx.x;
    const int t = threadIdx.x;
    const int wave = t >> 6, lane = t & 63;
    const float* xr = x + b * D;

    f32x4 xv[4];
    float s = 0.f;
#pragma unroll
    for (int i = 0; i < 4; ++i) {
        xv[i] = *(const f32x4*)(xr + i * 1024 + t * 4);
        s += xv[i].x * xv[i].x + xv[i].y * xv[i].y + xv[i].z * xv[i].z + xv[i].w * xv[i].w;
    }
#pragma unroll
    for (int m = 1; m < 64; m <<= 1) s += __shfl_xor(s, m, 64);

    __shared__ float wsum[4];
    if (lane == 0) wsum[wave] = s;
    __syncthreads();
    const float tot = wsum[0] + wsum[1] + wsum[2] + wsum[3];
    const float rs = rsqrtf(tot * (1.f / (float)D) + EPS);

#pragma unroll
    for (int i = 0; i < 4; ++i) {
        const int d = i * 1024 + t * 4;
        const f32x4 gv = *(const f32x4*)(g + d);
        f32x4 o;
        o.x = xv[i].x * rs * gv.x;
        o.y = xv[i].y * rs * gv.y;
        o.z = xv[i].z * rs * gv.z;
        o.w = xv[i].w * rs * gv.w;
        *(f32x4*)(h + b * D + d) = o;
    }
}

// ---- Kernel B: W via global_load_lds DMA (wave-private LDS), h VGPR dbuf ----
__global__ __launch_bounds__(256) void gemv_argmax_k(const float* __restrict__ W,
                                                     const float* __restrict__ h,
                                                     u64* __restrict__ partial) {
    __shared__ float wbuf[2][16][256];   // 32 KB; rows are wave-private
    const int lane = threadIdx.x & 63;
    const int wave = threadIdx.x >> 6;
    const int v0 = blockIdx.x * 16 + wave * VT;   // wave's 4 vocab rows
    const float* Wb = W + (size_t)v0 * D;
    const int dl = lane * 4;

    float acc[32];
#pragma unroll
    for (int i = 0; i < 32; ++i) acc[i] = 0.f;

    f32x4 hA[8], hB[8];   // h ping-pong (L2-hot, plain loads)

#define LOADH(HB, c)                                                           \
    {                                                                          \
        const int _d = (c) * 256 + dl;                                         \
        _Pragma("unroll")                                                      \
        for (int b = 0; b < 8; ++b)                                            \
            HB[b] = *(const f32x4*)(h + b * D + _d);                           \
    }

// one wave-issue per row: 64 lanes x 16B = the row's full 1KB chunk.
// LDS dest is the wave-uniform row base (HW writes base + lane*16).
#define DMA(p, c)                                                              \
    {                                                                          \
        _Pragma("unroll")                                                      \
        for (int vi = 0; vi < VT; ++vi) {                                      \
            const float* _src = Wb + (size_t)vi * D + (c) * 256 + dl;          \
            __builtin_amdgcn_global_load_lds(                                  \
                (const __attribute__((address_space(1))) void*)_src,           \
                (__attribute__((address_space(3))) void*)&wbuf[p][wave * VT + vi][0], \
                16, 0, 0);                                                     \
        }                                                                      \
    }

#define COMPUTE(HB, p)                                                         \
    {                                                                          \
        _Pragma("unroll")                                                      \
        for (int vi = 0; vi < VT; ++vi) {                                      \
            const f32x4 wv = *(const f32x4*)&wbuf[p][wave * VT + vi][dl];      \
            _Pragma("unroll")                                                  \
            for (int b = 0; b < 8; ++b)                                        \
                acc[b * VT + vi] += wv.x * HB[b].x + wv.y * HB[b].y +          \
                                    wv.z * HB[b].z + wv.w * HB[b].w;           \
        }                                                                      \
    }

// counted wait covering h(c) AND dma(c), leaving the 12 younger in flight;
// SB fences: issues pinned above, ds_read/FMA pinned below (rule #18).
#define WAIT12  SB; asm volatile("s_waitcnt vmcnt(12)" ::: "memory"); SB;
#define WAIT0   SB; asm volatile("s_waitcnt vmcnt(0)" ::: "memory"); SB;

    // prologue: chunk 0 in flight
    LOADH(hA, 0)
    DMA(0, 0)

#pragma unroll 1
    for (int c = 0; c <= 12; c += 2) {
        LOADH(hB, c + 1)
        DMA(1, c + 1)
        WAIT12              // retires h(c)+dma(c)
        COMPUTE(hA, 0)
        LOADH(hA, c + 2)    // c+2 <= 14
        DMA(0, c + 2)
        WAIT12              // retires h(c+1)+dma(c+1)
        COMPUTE(hB, 1)
    }
    // exit: computed through chunk 13; chunk 14 in flight (hA, buf0)
    LOADH(hB, 15)
    DMA(1, 15)
    WAIT12
    COMPUTE(hA, 0)          // chunk 14
    WAIT0
    COMPUTE(hB, 1)          // chunk 15
#undef LOADH
#undef DMA
#undef COMPUTE
#undef WAIT12
#undef WAIT0

    // Butterfly: 32 partials across 64 lanes -> lane l holds total for
    // j = l&31 (b = j>>2, vi = j&3). All indices compile-time.
#pragma unroll
    for (int s = 0; s < 5; ++s) {
        const int m = 1 << s;
        const bool bit = (lane & m) != 0;
#pragma unroll
        for (int u = 0; u < (32 >> (s + 1)); ++u) {
            const float a = acc[2 * u];
            const float c2 = acc[2 * u + 1];
            const float keep = bit ? c2 : a;
            const float send = bit ? a : c2;
            acc[u] = keep + __shfl_xor(send, m, 64);
        }
    }
    const float logit = acc[0] + __shfl_xor(acc[0], 32, 64);  // fold dup halves

    const int vidx = v0 + (lane & 3);
    const uint32_t fb = __float_as_uint(logit);
    const uint32_t key = (fb & 0x80000000u) ? ~fb : (fb | 0x80000000u);
    u64 best = ((u64)key << 32) | (uint32_t)(~(uint32_t)vidx);

    // merge across vi (bits 0,1); halves are duplicates after the fold
#pragma unroll
    for (int m = 1; m <= 2; m <<= 1) {
        const u64 o = __shfl_xor(best, m, 64);
        if (o > best) best = o;
    }
    {
        const u64 o = __shfl_xor(best, 32, 64);
        if (o > best) best = o;
    }

    __shared__ u64 lb[4][8];
    if (lane < 32 && (lane & 3) == 0) lb[wave][lane >> 2] = best;
    __syncthreads();
    if (threadIdx.x < 8) {
        const u64 m0 = lb[0][threadIdx.x], m1 = lb[1][threadIdx.x];
        const u64 m2 = lb[2][threadIdx.x], m3 = lb[3][threadIdx.x];
        const u64 a = m0 > m1 ? m0 : m1;
        const u64 b2 = m2 > m3 ? m2 : m3;
        partial[(size_t)blockIdx.x * 8 + threadIdx.x] = a > b2 ? a : b2;
    }
}

// ---------------- Kernel C: final argmax over block partials ----------------
__global__ __launch_bounds__(512) void finalize_k(const u64* __restrict__ partial,
                                                  int* __restrict__ out, int nblk) {
    const int b = threadIdx.x >> 6;   // one wave per batch row
    const int lane = threadIdx.x & 63;
    u64 best = 0ull;
    for (int p = lane; p < nblk; p += 64) {
        const u64 x = partial[(size_t)p * 8 + b];
        if (x > best) best = x;
    }
#pragma unroll
    for (int m = 1; m < 64; m <<= 1) {
        const u64 o = __shfl_xor(best, m, 64);
        if (o > best) best = o;
    }
    if (lane == 0) out[b] = (int)(~(uint32_t)best);
}

extern "C" void kernel_launch(void* const* d_in, const int* in_sizes, int n_in,
                              void* d_out, int out_size, void* d_ws, size_t ws_size,
                              hipStream_t stream) {
    const float* x = (const float*)d_in[0]; // hidden_states [8,4096]
    const float* g = (const float*)d_in[1]; // norm_weight [4096]
    const float* W = (const float*)d_in[2]; // lm_head_weight [32000,4096]
    int* out = (int*)d_out;                 // [8] int32 token ids

    float* h = (float*)d_ws;                                        // 128 KB
    u64* partial = (u64*)((char*)d_ws + BATCH * D * sizeof(float)); // 2000*8*8B

    rmsnorm_k<<<BATCH, 256, 0, stream>>>(x, g, h);
    gemv_argmax_k<<<NBLK, 256, 0, stream>>>(W, h, partial);
    finalize_k<<<1, 512, 0, stream>>>(partial, out, NBLK);
}